// Round 15
// baseline (238.023 us; speedup 1.0000x reference)
//
#include <hip/hip_runtime.h>

#define B_ 4
#define S_ 2048
#define D_ 1024
#define H_ 16
#define HS_ 64

typedef float f32x4 __attribute__((ext_vector_type(4)));
typedef short bf16x8 __attribute__((ext_vector_type(8)));

__device__ inline short f2bf(float f) {
  union { float f; unsigned u; } v; v.f = f;
  unsigned r = v.u + 0x7fffu + ((v.u >> 16) & 1u);
  return (short)(r >> 16);
}
__device__ inline unsigned fbits(float f) {
  union { float f; unsigned u; } v; v.f = f; return v.u;
}
// Raw v_exp_f32 (2^x). NOT __exp2f (glibc macro collision, r10 compile fail).
__device__ inline float fexp2(float x) { return __builtin_amdgcn_exp2f(x); }

__device__ inline void load_lds16(const short* g, short* l) {
  __builtin_amdgcn_global_load_lds((const __attribute__((address_space(1))) void*)g,
                                   (__attribute__((address_space(3))) void*)l, 16, 0, 0);
}

// fp32 -> bf16, 4 elems/thread.
__global__ __launch_bounds__(256) void cvt_f32_bf16(const float* __restrict__ in,
                                                    short* __restrict__ out, int n) {
  const int i = (blockIdx.x * 256 + threadIdx.x) * 4;
  if (i < n) {
    const float4 v = *(const float4*)(in + i);
    short4 o;
    o.x = f2bf(v.x); o.y = f2bf(v.y); o.z = f2bf(v.z); o.w = f2bf(v.w);
    *(short4*)(out + i) = o;
  }
}

// 4 weight matrices in one dispatch. grid (n/1024, 4).
__global__ __launch_bounds__(256) void cvt4_f32_bf16(const float* __restrict__ w0, const float* __restrict__ w1,
                                                     const float* __restrict__ w2, const float* __restrict__ w3,
                                                     short* __restrict__ o0, short* __restrict__ o1,
                                                     short* __restrict__ o2, short* __restrict__ o3, int n) {
  const float* in; short* out;
  switch (blockIdx.y) {
    case 0: in = w0; out = o0; break;
    case 1: in = w1; out = o1; break;
    case 2: in = w2; out = o2; break;
    default: in = w3; out = o3; break;
  }
  const int i = (blockIdx.x * 256 + threadIdx.x) * 4;
  if (i < n) {
    const float4 v = *(const float4*)(in + i);
    short4 o;
    o.x = f2bf(v.x); o.y = f2bf(v.y); o.z = f2bf(v.z); o.w = f2bf(v.w);
    *(short4*)(out + i) = o;
  }
}

// ---- BK=64 pipelined GEMM core (128^2, 2-phase, fallback paths) -------
__device__ inline void stage_tile64(const short* __restrict__ g, int ld, int k0,
                                    short* l, int tid) {
  const int srow = tid >> 3;
  const int scol = (tid & 7) * 8;
  const int scg  = ((tid & 7) ^ ((tid >> 3) & 7)) * 8;
  for (int j = 0; j < 4; j++)
    load_lds16(&g[(size_t)(srow + j * 32) * ld + k0 + scg], &l[(srow + j * 32) * 64 + scol]);
}

__device__ inline void mfma_core64(const short* lA, const short* lB, int wm, int wn,
                                   int col, int quad, f32x4 acc[4][4]) {
  for (int ks = 0; ks < 2; ks++) {
    const int cs = ((ks * 4 + quad) ^ (col & 7)) * 8;
    bf16x8 af[4], bfr[4];
    for (int i = 0; i < 4; i++) af[i]  = *(const bf16x8*)&lA[(wm + i * 16 + col) * 64 + cs];
    for (int j = 0; j < 4; j++) bfr[j] = *(const bf16x8*)&lB[(wn + j * 16 + col) * 64 + cs];
    for (int i = 0; i < 4; i++)
      for (int j = 0; j < 4; j++)
        acc[i][j] = __builtin_amdgcn_mfma_f32_16x16x32_bf16(af[i], bfr[j], acc[i][j], 0, 0, 0);
  }
}

// Generic bf16 GEMM (fallback): BK=64, dbuf, 2-phase. grid (M/128, N/128).
template <bool CF32>
__global__ __launch_bounds__(256) void gemm_bb(const short* __restrict__ A,
                                               const short* __restrict__ Bt,
                                               void* __restrict__ Cv,
                                               const float* __restrict__ bias,
                                               int M, int N, int K) {
  __shared__ __align__(16) short lA[2][128 * 64];
  __shared__ __align__(16) short lB[2][128 * 64];
  const int tid = threadIdx.x;
  const int wave = tid >> 6, lane = tid & 63;
  const int quad = lane >> 4, col = lane & 15;
  const int m0 = blockIdx.x * 128, n0 = blockIdx.y * 128;
  const int wm = (wave >> 1) * 64, wn = (wave & 1) * 64;

  f32x4 acc[4][4];
  for (int i = 0; i < 4; i++)
    for (int j = 0; j < 4; j++) acc[i][j] = (f32x4){0.f, 0.f, 0.f, 0.f};

  const int NT = K >> 6;
  stage_tile64(&A[(size_t)m0 * K], K, 0, lA[0], tid);
  stage_tile64(&Bt[(size_t)n0 * K], K, 0, lB[0], tid);
  __syncthreads();
  for (int kt = 0; kt < NT; kt++) {
    const int cur = kt & 1;
    if (kt + 1 < NT) {
      stage_tile64(&A[(size_t)m0 * K], K, (kt + 1) * 64, lA[cur ^ 1], tid);
      stage_tile64(&Bt[(size_t)n0 * K], K, (kt + 1) * 64, lB[cur ^ 1], tid);
    }
    mfma_core64(lA[cur], lB[cur], wm, wn, col, quad, acc);
    __syncthreads();
  }

  for (int j = 0; j < 4; j++) {
    const int gn = n0 + wn + j * 16 + col;
    const float bv = bias ? bias[gn] : 0.f;
    for (int i = 0; i < 4; i++) {
      const int gm = m0 + wm + i * 16 + quad * 4;
      for (int r = 0; r < 4; r++) {
        if (CF32) ((float*)Cv)[(size_t)(gm + r) * N + gn] = acc[i][j][r] + bv;
        else      ((short*)Cv)[(size_t)(gm + r) * N + gn] = f2bf(acc[i][j][r] + bv);
      }
    }
  }
}

// ---- v4 pipelined core: BM=128 x BN=256, triple-buffered, counted vmcnt,
// ONE barrier per K-tile. r14 post-mortem: 4 BAR + 2 lgkm/tile with 8
// lockstep waves at 1 block/CU left ~2K dead cyc/tile (MfmaUtil 31, VALU 20).
// Dependence audit: reads all hit buf[t%3]; stages hit buf[(t+2)%3] ==
// buf[(t-1)%3], whose readers finished before the end-of-tile-(t-1) barrier
// (per-wave lgkm(0) precedes its MFMAs precedes the barrier) -> intra-tile
// barriers removable. Per tile: {16 ds_reads; 6 stages; lgkm(0); 32 MFMA;
// gate vmcnt(6); BAR}. Ledger & gate unchanged from r9/r14-verified v3.
// grid (M/128, 12) -- BM=128.
__global__ __launch_bounds__(512, 2) void gemm_qkv8(const short* __restrict__ A,
                                                    const short* Wq, const short* Wk, const short* Wv,
                                                    short* Cq, short* Ck, short* Cvt) {
  __shared__ __align__(16) short lds[3][24576];  // [buf][A 128x64 | B 256x64]
  const int tid = threadIdx.x;
  const int wave = tid >> 6, lane = tid & 63;
  const int quad = lane >> 4, col = lane & 15;
  const int nsel = blockIdx.y >> 2;
  const int n0 = (blockIdx.y & 3) * 256;
  const short* Bt = nsel == 0 ? Wq : (nsel == 1 ? Wk : Wv);
  const int m0 = blockIdx.x * 128;
  const int wm = (wave >> 2) * 64, wn = (wave & 3) * 64;
  const int K = D_;
  const int NT = 16;  // K/64

  const int srow = tid >> 3;   // 0..63
  const int sc8 = tid & 7;
  const short* gA = &A[(size_t)m0 * K];
  const short* gB = &Bt[(size_t)n0 * K];

  auto stageA = [&](int t, int p) {  // p = 0..1 (64 rows each)
    const int row = p * 64 + srow;
    load_lds16(&gA[(size_t)row * K + t * 64 + ((sc8 ^ (row & 7)) * 8)],
               &lds[t % 3][row * 64 + sc8 * 8]);
  };
  auto stageB = [&](int t, int p) {  // p = 0..3 (64 rows each)
    const int row = p * 64 + srow;
    load_lds16(&gB[(size_t)row * K + t * 64 + ((sc8 ^ (row & 7)) * 8)],
               &lds[t % 3][8192 + row * 64 + sc8 * 8]);
  };

  f32x4 acc[4][4];
#pragma unroll
  for (int i = 0; i < 4; i++)
#pragma unroll
    for (int j = 0; j < 4; j++) acc[i][j] = (f32x4){0.f, 0.f, 0.f, 0.f};

  // Prologue: tile0 (6 loads, oldest) then tile1 (6).
  stageA(0, 0); stageA(0, 1);
  for (int p = 0; p < 4; p++) stageB(0, p);
  stageA(1, 0); stageA(1, 1);
  for (int p = 0; p < 4; p++) stageB(1, p);
  asm volatile("s_waitcnt vmcnt(6)" ::: "memory");  // tile0's 6 landed
  __builtin_amdgcn_sched_barrier(0);
  __builtin_amdgcn_s_barrier();

  for (int t = 0; t < NT; t++) {
    const short* la = lds[t % 3];
    const short* lb = la + 8192;

    bf16x8 af[4][2], bfr[4][2];
#pragma unroll
    for (int j = 0; j < 4; j++)
#pragma unroll
      for (int kk = 0; kk < 2; kk++)
        bfr[j][kk] = *(const bf16x8*)&lb[(wn + j * 16 + col) * 64 +
                                         (((kk * 4 + quad) ^ (col & 7)) * 8)];
#pragma unroll
    for (int f = 0; f < 4; f++)
#pragma unroll
      for (int kk = 0; kk < 2; kk++)
        af[f][kk] = *(const bf16x8*)&la[(wm + f * 16 + col) * 64 +
                                        (((kk * 4 + quad) ^ (col & 7)) * 8)];
    if (t + 2 < NT) {
      stageB(t + 2, 0); stageB(t + 2, 1); stageB(t + 2, 2); stageB(t + 2, 3);
      stageA(t + 2, 0); stageA(t + 2, 1);
    }
    __builtin_amdgcn_sched_barrier(0);
    asm volatile("s_waitcnt lgkmcnt(0)" ::: "memory");
    __builtin_amdgcn_sched_barrier(0);
    __builtin_amdgcn_s_setprio(1);
#pragma unroll
    for (int f = 0; f < 4; f++)
#pragma unroll
      for (int j = 0; j < 4; j++)
#pragma unroll
        for (int kk = 0; kk < 2; kk++)
          acc[f][j] = __builtin_amdgcn_mfma_f32_16x16x32_bf16(
              af[f][kk], bfr[j][kk], acc[f][j], 0, 0, 0);
    __builtin_amdgcn_s_setprio(0);
    if (t + 2 < NT)      { asm volatile("s_waitcnt vmcnt(6)" ::: "memory"); }
    else if (t + 1 < NT) { asm volatile("s_waitcnt vmcnt(0)" ::: "memory"); }
    __builtin_amdgcn_sched_barrier(0);
    __builtin_amdgcn_s_barrier();
  }

  if (nsel < 2) {
    short* C = nsel ? Ck : Cq;
    const float sc = nsel == 0 ? 0.18033688f : 1.0f;  // 0.125 * log2(e)
    for (int j = 0; j < 4; j++) {
      const int gn = n0 + wn + j * 16 + col;
      for (int i = 0; i < 4; i++) {
        const int gm = m0 + wm + i * 16 + quad * 4;
        for (int r = 0; r < 4; r++)
          C[(size_t)(gm + r) * D_ + gn] = f2bf(acc[i][j][r] * sc);
      }
    }
  } else {
    for (int j = 0; j < 4; j++) {
      const int gn = n0 + wn + j * 16 + col;
      for (int i = 0; i < 4; i++) {
        const int gm = m0 + wm + i * 16 + quad * 4;
        const int bb = gm >> 11, s = gm & 2047;
        short4 o;
        o.x = f2bf(acc[i][j][0]); o.y = f2bf(acc[i][j][1]);
        o.z = f2bf(acc[i][j][2]); o.w = f2bf(acc[i][j][3]);
        *(short4*)&Cvt[((size_t)bb * D_ + gn) * (size_t)S_ + s] = o;
      }
    }
  }
}

// Output projection, v4 single-barrier schedule (same transformation).
// grid (M/128, N/256) = (64, 4) = 256 blocks = exactly 1 resident round.
__global__ __launch_bounds__(512, 2) void gemm_bb8(const short* __restrict__ A,
                                                   const short* __restrict__ Bt,
                                                   float* __restrict__ C,
                                                   const float* __restrict__ bias) {
  __shared__ __align__(16) short lds[3][24576];  // [buf][A 128x64 | B 256x64]
  const int tid = threadIdx.x;
  const int wave = tid >> 6, lane = tid & 63;
  const int quad = lane >> 4, col = lane & 15;
  const int n0 = blockIdx.y * 256;
  const int m0 = blockIdx.x * 128;
  const int wm = (wave >> 2) * 64, wn = (wave & 3) * 64;
  const int K = D_, N = D_;
  const int NT = 16;  // K/64

  const int srow = tid >> 3;
  const int sc8 = tid & 7;
  const short* gA = &A[(size_t)m0 * K];
  const short* gB = &Bt[(size_t)n0 * K];

  auto stageA = [&](int t, int p) {
    const int row = p * 64 + srow;
    load_lds16(&gA[(size_t)row * K + t * 64 + ((sc8 ^ (row & 7)) * 8)],
               &lds[t % 3][row * 64 + sc8 * 8]);
  };
  auto stageB = [&](int t, int p) {
    const int row = p * 64 + srow;
    load_lds16(&gB[(size_t)row * K + t * 64 + ((sc8 ^ (row & 7)) * 8)],
               &lds[t % 3][8192 + row * 64 + sc8 * 8]);
  };

  f32x4 acc[4][4];
#pragma unroll
  for (int i = 0; i < 4; i++)
#pragma unroll
    for (int j = 0; j < 4; j++) acc[i][j] = (f32x4){0.f, 0.f, 0.f, 0.f};

  stageA(0, 0); stageA(0, 1);
  for (int p = 0; p < 4; p++) stageB(0, p);
  stageA(1, 0); stageA(1, 1);
  for (int p = 0; p < 4; p++) stageB(1, p);
  asm volatile("s_waitcnt vmcnt(6)" ::: "memory");
  __builtin_amdgcn_sched_barrier(0);
  __builtin_amdgcn_s_barrier();

  for (int t = 0; t < NT; t++) {
    const short* la = lds[t % 3];
    const short* lb = la + 8192;

    bf16x8 af[4][2], bfr[4][2];
#pragma unroll
    for (int j = 0; j < 4; j++)
#pragma unroll
      for (int kk = 0; kk < 2; kk++)
        bfr[j][kk] = *(const bf16x8*)&lb[(wn + j * 16 + col) * 64 +
                                         (((kk * 4 + quad) ^ (col & 7)) * 8)];
#pragma unroll
    for (int f = 0; f < 4; f++)
#pragma unroll
      for (int kk = 0; kk < 2; kk++)
        af[f][kk] = *(const bf16x8*)&la[(wm + f * 16 + col) * 64 +
                                        (((kk * 4 + quad) ^ (col & 7)) * 8)];
    if (t + 2 < NT) {
      stageB(t + 2, 0); stageB(t + 2, 1); stageB(t + 2, 2); stageB(t + 2, 3);
      stageA(t + 2, 0); stageA(t + 2, 1);
    }
    __builtin_amdgcn_sched_barrier(0);
    asm volatile("s_waitcnt lgkmcnt(0)" ::: "memory");
    __builtin_amdgcn_sched_barrier(0);
    __builtin_amdgcn_s_setprio(1);
#pragma unroll
    for (int f = 0; f < 4; f++)
#pragma unroll
      for (int j = 0; j < 4; j++)
#pragma unroll
        for (int kk = 0; kk < 2; kk++)
          acc[f][j] = __builtin_amdgcn_mfma_f32_16x16x32_bf16(
              af[f][kk], bfr[j][kk], acc[f][j], 0, 0, 0);
    __builtin_amdgcn_s_setprio(0);
    if (t + 2 < NT)      { asm volatile("s_waitcnt vmcnt(6)" ::: "memory"); }
    else if (t + 1 < NT) { asm volatile("s_waitcnt vmcnt(0)" ::: "memory"); }
    __builtin_amdgcn_sched_barrier(0);
    __builtin_amdgcn_s_barrier();
  }

  for (int j = 0; j < 4; j++) {
    const int gn = n0 + wn + j * 16 + col;
    const float bv = bias[gn];
    for (int i = 0; i < 4; i++) {
      const int gm = m0 + wm + i * 16 + quad * 4;
      for (int r = 0; r < 4; r++)
        C[(size_t)(gm + r) * N + gn] = acc[i][j][r] + bv;
    }
  }
}

// Flash attention v10: raw v_exp_f32 via __builtin_amdgcn_exp2f (verified
// r14: flash dropped out of top-5, est ~64us from total delta).
__global__ __launch_bounds__(256) void flash_attn6(const short* __restrict__ Q,
                                                   const short* __restrict__ Kt,
                                                   const short* __restrict__ Vt,
                                                   short* __restrict__ O) {
  __shared__ __align__(16) short lK[2][64 * 64];
  __shared__ __align__(16) short lV[2][64 * 64];
  __shared__ __align__(16) short pl[4][16 * 64];
  const int tid = threadIdx.x, wave = tid >> 6, lane = tid & 63;
  const int quad = lane >> 4, col = lane & 15;
  const int bh = blockIdx.x;
  const int b = bh >> 4, h = bh & 15;
  const size_t qkbase = (size_t)b * S_ * D_ + (size_t)h * HS_;
  const size_t vtbase = ((size_t)b * D_ + (size_t)h * HS_) * (size_t)S_;

  const int srow = tid >> 3;
  const int scg = (tid & 7) ^ (srow & 7);
  const int cs0 = (quad ^ (col & 7)) * 8;
  const int cs1 = ((quad + 4) ^ (col & 7)) * 8;
  short* plw = pl[wave];

  bf16x8 ones;
  for (int i = 0; i < 8; i++) ones[i] = (short)0x3F80;

  int nb = 0;

  for (int half = 0; half < 2; half++) {
    const int s = half ? (int)blockIdx.y : 31 - (int)blockIdx.y;
    const int qmin = s * 64 + wave * 16;
    const int L = s;

    load_lds16(&Kt[qkbase + (size_t)srow * D_ + scg * 8],        &lK[nb][tid * 8]);
    load_lds16(&Kt[qkbase + (size_t)(32 + srow) * D_ + scg * 8], &lK[nb][2048 + tid * 8]);
    load_lds16(&Vt[vtbase + (size_t)srow * S_ + scg * 8],        &lV[nb][tid * 8]);
    load_lds16(&Vt[vtbase + (size_t)(srow + 32) * S_ + scg * 8], &lV[nb][2048 + tid * 8]);
    const int cur0 = nb;
    nb ^= 1;

    bf16x8 qf[2];
    for (int x = 0; x < 2; x++)
      qf[x] = *(const bf16x8*)&Q[qkbase + (size_t)(qmin + col) * D_ + x * 32 + quad * 8];

    f32x4 oacc[4], lacc;
    for (int dt = 0; dt < 4; dt++) oacc[dt] = (f32x4){0.f, 0.f, 0.f, 0.f};
    lacc = (f32x4){0.f, 0.f, 0.f, 0.f};

    for (int nt = 0; nt <= L; nt++) {
      const int n0 = nt * 64;
      const int cur = cur0 ^ (nt & 1);
      __syncthreads();
      if (nt < L) {
        const int nn = n0 + 64;
        load_lds16(&Kt[qkbase + (size_t)(nn + srow) * D_ + scg * 8],      &lK[nb][tid * 8]);
        load_lds16(&Kt[qkbase + (size_t)(nn + 32 + srow) * D_ + scg * 8], &lK[nb][2048 + tid * 8]);
        load_lds16(&Vt[vtbase + (size_t)srow * S_ + nn + scg * 8],        &lV[nb][tid * 8]);
        load_lds16(&Vt[vtbase + (size_t)(srow + 32) * S_ + nn + scg * 8], &lV[nb][2048 + tid * 8]);
        nb ^= 1;
      }

      const short* lKc = lK[cur];
      const short* lVc = lV[cur];
      const bool needM = (nt == L);

      bf16x8 kf[4][2];
      for (int t = 0; t < 4; t++) {
        const int rb = (t * 16 + col) * 64;
        kf[t][0] = *(const bf16x8*)&lKc[rb + cs0];
        kf[t][1] = *(const bf16x8*)&lKc[rb + cs1];
      }

      const int qg = qmin + col;
      for (int t = 0; t < 4; t++) {
        f32x4 z = (f32x4){0.f, 0.f, 0.f, 0.f};
        __builtin_amdgcn_s_setprio(1);
        z = __builtin_amdgcn_mfma_f32_16x16x32_bf16(kf[t][0], qf[0], z, 0, 0, 0);
        z = __builtin_amdgcn_mfma_f32_16x16x32_bf16(kf[t][1], qf[1], z, 0, 0, 0);
        __builtin_amdgcn_s_setprio(0);
        float p0 = fexp2(z[0]);
        float p1 = fexp2(z[1]);
        float p2 = fexp2(z[2]);
        float p3 = fexp2(z[3]);
        if (needM) {
          const int kv = n0 + t * 16 + quad * 4;
          if (kv + 0 > qg) p0 = 0.f;
          if (kv + 1 > qg) p1 = 0.f;
          if (kv + 2 > qg) p2 = 0.f;
          if (kv + 3 > qg) p3 = 0.f;
        }
        unsigned d0 = __builtin_amdgcn_perm(fbits(p1), fbits(p0), 0x07060302u);
        unsigned d1 = __builtin_amdgcn_perm(fbits(p3), fbits(p2), 0x07060302u);
        const int cc = (2 * t + (quad >> 1)) ^ (col & 7);
        uint2 w; w.x = d0; w.y = d1;
        *(uint2*)&plw[col * 64 + cc * 8 + (quad & 1) * 4] = w;
      }

      for (int h2 = 0; h2 < 2; h2++) {
        const int cgo = ((h2 * 4 + quad) ^ (col & 7)) * 8;
        const bf16x8 pf = *(const bf16x8*)&plw[col * 64 + cgo];
        bf16x8 vf[4];
        for (int dt = 0; dt < 4; dt++)
          vf[dt] = *(const bf16x8*)&lVc[(dt * 16 + col) * 64 + cgo];
        __builtin_amdgcn_s_setprio(1);
        lacc = __builtin_amdgcn_mfma_f32_16x16x32_bf16(pf, ones, lacc, 0, 0, 0);
        for (int dt = 0; dt < 4; dt++)
          oacc[dt] = __builtin_amdgcn_mfma_f32_16x16x32_bf16(pf, vf[dt], oacc[dt], 0, 0, 0);
        __builtin_amdgcn_s_setprio(0);
      }
    }

    for (int r = 0; r < 4; r++) {
      const float inv = 1.f / lacc[r];
      const size_t row = qkbase + (size_t)(qmin + quad * 4 + r) * D_;
      for (int dt = 0; dt < 4; dt++)
        O[row + dt * 16 + col] = f2bf(oacc[dt][r] * inv);
    }
  }
}

// ---- legacy fallback kernels (small-ws paths) ----
__global__ __launch_bounds__(256) void gemm_ff(const float* __restrict__ A,
                                               const float* __restrict__ Bt,
                                               short* __restrict__ C,
                                               int M, int N, int K) {
  __shared__ __align__(16) short lA[128 * 32];
  __shared__ __align__(16) short lB[128 * 32];
  const int tid = threadIdx.x;
  const int wave = tid >> 6, lane = tid & 63;
  const int quad = lane >> 4, col = lane & 15;
  const int m0 = blockIdx.y * 128, n0 = blockIdx.x * 128;
  const int wm = (wave >> 1) * 64, wn = (wave & 1) * 64;
  const int srow2 = tid >> 1;
  const int sc = (tid & 1) * 16;

  f32x4 acc[4][4];
  for (int i = 0; i < 4; i++)
    for (int j = 0; j < 4; j++) acc[i][j] = (f32x4){0.f, 0.f, 0.f, 0.f};

  for (int k0 = 0; k0 < K; k0 += 32) {
    __syncthreads();
    {
      const float4* ga = (const float4*)&A[(size_t)(m0 + srow2) * K + k0 + sc];
      const float4 v0 = ga[0], v1 = ga[1], v2 = ga[2], v3 = ga[3];
      bf16x8 p0, p1;
      p0[0] = f2bf(v0.x); p0[1] = f2bf(v0.y); p0[2] = f2bf(v0.z); p0[3] = f2bf(v0.w);
      p0[4] = f2bf(v1.x); p0[5] = f2bf(v1.y); p0[6] = f2bf(v1.z); p0[7] = f2bf(v1.w);
      p1[0] = f2bf(v2.x); p1[1] = f2bf(v2.y); p1[2] = f2bf(v2.z); p1[3] = f2bf(v2.w);
      p1[4] = f2bf(v3.x); p1[5] = f2bf(v3.y); p1[6] = f2bf(v3.z); p1[7] = f2bf(v3.w);
      *(bf16x8*)&lA[srow2 * 32 + sc]     = p0;
      *(bf16x8*)&lA[srow2 * 32 + sc + 8] = p1;
    }
    {
      const float4* gb = (const float4*)&Bt[(size_t)(n0 + srow2) * K + k0 + sc];
      const float4 v0 = gb[0], v1 = gb[1], v2 = gb[2], v3 = gb[3];
      bf16x8 p0, p1;
      p0[0] = f2bf(v0.x); p0[1] = f2bf(v0.y); p0[2] = f2bf(v0.z); p0[3] = f2bf(v0.w);
      p0[4] = f2bf(v1.x); p0[5] = f2bf(v1.y); p0[6] = f2bf(v1.z); p0[7] = f2bf(v1.w);
      p1[0] = f2bf(v2.x); p1[1] = f2bf(v2.y); p1[2] = f2bf(v2.z); p1[3] = f2bf(v2.w);
      p1[4] = f2bf(v3.x); p1[5] = f2bf(v3.y); p1[6] = f2bf(v3.z); p1[7] = f2bf(v3.w);
      *(bf16x8*)&lB[srow2 * 32 + sc]     = p0;
      *(bf16x8*)&lB[srow2 * 32 + sc + 8] = p1;
    }
    __syncthreads();
    {
      bf16x8 af[4], bfr[4];
      for (int i = 0; i < 4; i++) af[i]  = *(const bf16x8*)&lA[(wm + i * 16 + col) * 32 + quad * 8];
      for (int j = 0; j < 4; j++) bfr[j] = *(const bf16x8*)&lB[(wn + j * 16 + col) * 32 + quad * 8];
      for (int i = 0; i < 4; i++)
        for (int j = 0; j < 4; j++)
          acc[i][j] = __builtin_amdgcn_mfma_f32_16x16x32_bf16(af[i], bfr[j], acc[i][j], 0, 0, 0);
    }
  }

  for (int j = 0; j < 4; j++) {
    const int gn = n0 + wn + j * 16 + col;
    for (int i = 0; i < 4; i++) {
      const int gm = m0 + wm + i * 16 + quad * 4;
      for (int r = 0; r < 4; r++)
        C[(size_t)(gm + r) * N + gn] = f2bf(acc[i][j][r]);
    }
  }
}

__global__ __launch_bounds__(256) void gemm_out_bf(const short* __restrict__ A,
                                                   const float* __restrict__ Bt,
                                                   float* __restrict__ C,
                                                   const float* __restrict__ bias,
                                                   int M, int N, int K) {
  __shared__ __align__(16) short lA[128 * 32];
  __shared__ __align__(16) short lB[128 * 32];
  const int tid = threadIdx.x;
  const int wave = tid >> 6, lane = tid & 63;
  const int quad = lane >> 4, col = lane & 15;
  const int m0 = blockIdx.y * 128, n0 = blockIdx.x * 128;
  const int wm = (wave >> 1) * 64, wn = (wave & 1) * 64;
  const int srow = wave * 32 + (lane >> 2);
  const int scol = (lane & 3) * 8;
  const int srow2 = tid >> 1;
  const int sc = (tid & 1) * 16;

  f32x4 acc[4][4];
  for (int i = 0; i < 4; i++)
    for (int j = 0; j < 4; j++) acc[i][j] = (f32x4){0.f, 0.f, 0.f, 0.f};

  for (int k0 = 0; k0 < K; k0 += 32) {
    __syncthreads();
    load_lds16(&A[(size_t)(m0 + srow) * K + k0 + scol],      &lA[srow * 32 + scol]);
    load_lds16(&A[(size_t)(m0 + srow + 16) * K + k0 + scol], &lA[(srow + 16) * 32 + scol]);
    {
      const float4* gb = (const float4*)&Bt[(size_t)(n0 + srow2) * K + k0 + sc];
      const float4 v0 = gb[0], v1 = gb[1], v2 = gb[2], v3 = gb[3];
      bf16x8 p0, p1;
      p0[0] = f2bf(v0.x); p0[1] = f2bf(v0.y); p0[2] = f2bf(v0.z); p0[3] = f2bf(v0.w);
      p0[4] = f2bf(v1.x); p0[5] = f2bf(v1.y); p0[6] = f2bf(v1.z); p0[7] = f2bf(v1.w);
      p1[0] = f2bf(v2.x); p1[1] = f2bf(v2.y); p1[2] = f2bf(v2.z); p1[3] = f2bf(v2.w);
      p1[4] = f2bf(v3.x); p1[5] = f2bf(v3.y); p1[6] = f2bf(v3.z); p1[7] = f2bf(v3.w);
      *(bf16x8*)&lB[srow2 * 32 + sc]     = p0;
      *(bf16x8*)&lB[srow2 * 32 + sc + 8] = p1;
    }
    __syncthreads();
    {
      bf16x8 af[4], bfr[4];
      for (int i = 0; i < 4; i++) af[i]  = *(const bf16x8*)&lA[(wm + i * 16 + col) * 32 + quad * 8];
      for (int j = 0; j < 4; j++) bfr[j] = *(const bf16x8*)&lB[(wn + j * 16 + col) * 32 + quad * 8];
      for (int i = 0; i < 4; i++)
        for (int j = 0; j < 4; j++)
          acc[i][j] = __builtin_amdgcn_mfma_f32_16x16x32_bf16(af[i], bfr[j], acc[i][j], 0, 0, 0);
    }
  }

  for (int j = 0; j < 4; j++) {
    const int gn = n0 + wn + j * 16 + col;
    const float bv = bias ? bias[gn] : 0.f;
    for (int i = 0; i < 4; i++) {
      const int gm = m0 + wm + i * 16 + quad * 4;
      for (int r = 0; r < 4; r++)
        C[(size_t)(gm + r) * N + gn] = acc[i][j][r] + bv;
    }
  }
}

__global__ __launch_bounds__(64) void flash_attn(const short* __restrict__ Q,
                                                 const short* __restrict__ K,
                                                 const short* __restrict__ V,
                                                 short* __restrict__ O) {
  __shared__ __align__(16) short pl[16 * 40];
  const int lane = threadIdx.x;
  const int quad = lane >> 4, col = lane & 15;
  const int blk = blockIdx.x;
  const int qt = blk & 127;
  const int bh = blk >> 7;
  const int b = bh >> 4, h = bh & 15;
  const int q0 = qt * 16;
  const size_t base = (size_t)b * S_ * D_ + (size_t)h * HS_;

  const bf16x8 qf0 = *(const bf16x8*)&Q[base + (size_t)(q0 + col) * D_ + quad * 8];
  const bf16x8 qf1 = *(const bf16x8*)&Q[base + (size_t)(q0 + col) * D_ + 32 + quad * 8];

  float mr[4], lr[4];
  f32x4 oacc[4];
  for (int r = 0; r < 4; r++) { mr[r] = -1e30f; lr[r] = 0.f; }
  for (int dt = 0; dt < 4; dt++) oacc[dt] = (f32x4){0.f, 0.f, 0.f, 0.f};

  const int ntiles = (q0 + 15) / 32 + 1;
  for (int nt = 0; nt < ntiles; nt++) {
    const int n0 = nt * 32;
    f32x4 s[2];
    s[0] = (f32x4){0.f, 0.f, 0.f, 0.f};
    s[1] = (f32x4){0.f, 0.f, 0.f, 0.f};
    for (int t = 0; t < 2; t++) {
      const short* kp = &K[base + (size_t)(n0 + t * 16 + col) * D_ + quad * 8];
      const bf16x8 kf0 = *(const bf16x8*)kp;
      const bf16x8 kf1 = *(const bf16x8*)(kp + 32);
      s[t] = __builtin_amdgcn_mfma_f32_16x16x32_bf16(qf0, kf0, s[t], 0, 0, 0);
      s[t] = __builtin_amdgcn_mfma_f32_16x16x32_bf16(qf1, kf1, s[t], 0, 0, 0);
    }
    for (int r = 0; r < 4; r++) {
      const int mg = q0 + quad * 4 + r;
      float s0 = s[0][r] * 0.125f; if (n0 + col > mg)      s0 = -1e30f;
      float s1 = s[1][r] * 0.125f; if (n0 + 16 + col > mg) s1 = -1e30f;
      float tm = fmaxf(s0, s1);
      for (int off = 1; off < 16; off <<= 1) tm = fmaxf(tm, __shfl_xor(tm, off));
      const float mnew = fmaxf(mr[r], tm);
      const float alpha = __expf(mr[r] - mnew);
      mr[r] = mnew;
      const float p0 = __expf(s0 - mnew);
      const float p1 = __expf(s1 - mnew);
      float ps = p0 + p1;
      for (int off = 1; off < 16; off <<= 1) ps += __shfl_xor(ps, off);
      lr[r] = lr[r] * alpha + ps;
      for (int dt = 0; dt < 4; dt++) oacc[dt][r] *= alpha;
      pl[(quad * 4 + r) * 40 + col]      = f2bf(p0);
      pl[(quad * 4 + r) * 40 + 16 + col] = f2bf(p1);
    }
    const bf16x8 pf = *(const bf16x8*)&pl[col * 40 + quad * 8];
    for (int dt = 0; dt < 4; dt++) {
      bf16x8 vf;
      const short* vp = &V[base + (size_t)(n0 + quad * 8) * D_ + dt * 16 + col];
      for (int j = 0; j < 8; j++) vf[j] = vp[(size_t)j * D_];
      oacc[dt] = __builtin_amdgcn_mfma_f32_16x16x32_bf16(pf, vf, oacc[dt], 0, 0, 0);
    }
  }

  for (int r = 0; r < 4; r++) {
    const float inv = 1.f / lr[r];
    const size_t row = base + (size_t)(q0 + quad * 4 + r) * D_;
    for (int dt = 0; dt < 4; dt++)
      O[row + dt * 16 + col] = f2bf(oacc[dt][r] * inv);
  }
}

extern "C" void kernel_launch(void* const* d_in, const int* in_sizes, int n_in,
                              void* d_out, int out_size, void* d_ws, size_t ws_size,
                              hipStream_t stream) {
  const float* x  = (const float*)d_in[0];
  const float* Wk = (const float*)d_in[1];
  const float* Wq = (const float*)d_in[2];
  const float* Wv = (const float*)d_in[3];
  const float* Wo = (const float*)d_in[4];
  const float* bo = (const float*)d_in[5];
  float* out = (float*)d_out;

  char* ws = (char*)d_ws;
  const size_t MiB = 1u << 20;
  const int M = B_ * S_, N = D_, K = D_;
  const int nx = M * D_, nw = D_ * D_;

  if (ws_size >= 88 * MiB) {
    short* xb    = (short*)(ws);
    short* wkb   = (short*)(ws + 16 * MiB);
    short* wqb   = (short*)(ws + 18 * MiB);
    short* wvb   = (short*)(ws + 20 * MiB);
    short* wob   = (short*)(ws + 22 * MiB);
    short* q_ws  = (short*)(ws + 24 * MiB);
    short* k_ws  = (short*)(ws + 40 * MiB);
    short* vt_ws = (short*)(ws + 56 * MiB);
    short* a_ws  = (short*)(ws + 72 * MiB);

    hipLaunchKernelGGL(cvt_f32_bf16, dim3(nx / 1024), dim3(256), 0, stream, x, xb, nx);
    hipLaunchKernelGGL(cvt4_f32_bf16, dim3(nw / 1024, 4), dim3(256), 0, stream,
                       Wq, Wk, Wv, Wo, wqb, wkb, wvb, wob, nw);
    hipLaunchKernelGGL(gemm_qkv8, dim3(M / 128, 12), dim3(512), 0, stream,
                       xb, wqb, wkb, wvb, q_ws, k_ws, vt_ws);
    hipLaunchKernelGGL(flash_attn6, dim3(B_ * H_, 16), dim3(256), 0, stream,
                       q_ws, k_ws, vt_ws, a_ws);
    hipLaunchKernelGGL(gemm_bb8, dim3(M / 128, N / 256), dim3(512), 0, stream,
                       a_ws, wob, out, bo);
  } else if (ws_size >= 64 * MiB) {
    short* q_ws = (short*)(ws);
    short* k_ws = (short*)(ws + 16 * MiB);
    short* v_ws = (short*)(ws + 32 * MiB);
    short* a_ws = (short*)(ws + 48 * MiB);
    dim3 gg(N / 128, M / 128), gb(256);
    hipLaunchKernelGGL(gemm_ff, gg, gb, 0, stream, x, Wq, q_ws, M, N, K);
    hipLaunchKernelGGL(gemm_ff, gg, gb, 0, stream, x, Wk, k_ws, M, N, K);
    hipLaunchKernelGGL(gemm_ff, gg, gb, 0, stream, x, Wv, v_ws, M, N, K);
    hipLaunchKernelGGL(flash_attn, dim3(B_ * H_ * (S_ / 16)), dim3(64), 0, stream, q_ws, k_ws, v_ws, a_ws);
    hipLaunchKernelGGL(gemm_out_bf, gg, gb, 0, stream, a_ws, Wo, out, bo, M, N, K);
  } else {
    short* q_ws = (short*)(ws);
    short* k_ws = (short*)(ws + 4 * MiB);
    short* v_ws = (short*)(ws + 8 * MiB);
    short* a_ws = (short*)(ws + 12 * MiB);
    const int Mb = S_;
    dim3 gg(N / 128, Mb / 128), gb(256);
    for (int b = 0; b < B_; b++) {
      const float* xb = x + (size_t)b * S_ * D_;
      float* ob = out + (size_t)b * S_ * D_;
      hipLaunchKernelGGL(gemm_ff, gg, gb, 0, stream, xb, Wq, q_ws, Mb, N, K);
      hipLaunchKernelGGL(gemm_ff, gg, gb, 0, stream, xb, Wk, k_ws, Mb, N, K);
      hipLaunchKernelGGL(gemm_ff, gg, gb, 0, stream, xb, Wv, v_ws, Mb, N, K);
      hipLaunchKernelGGL(flash_attn, dim3(H_ * (S_ / 16)), dim3(64), 0, stream, q_ws, k_ws, v_ws, a_ws);
      hipLaunchKernelGGL(gemm_out_bf, gg, gb, 0, stream, a_ws, Wo, ob, bo, Mb, N, K);
    }
  }
}

// Round 16
// 222.805 us; speedup vs baseline: 1.0683x; 1.0683x over previous
//
#include <hip/hip_runtime.h>

#define B_ 4
#define S_ 2048
#define D_ 1024
#define H_ 16
#define HS_ 64

typedef float f32x4 __attribute__((ext_vector_type(4)));
typedef short bf16x8 __attribute__((ext_vector_type(8)));

__device__ inline short f2bf(float f) {
  union { float f; unsigned u; } v; v.f = f;
  unsigned r = v.u + 0x7fffu + ((v.u >> 16) & 1u);
  return (short)(r >> 16);
}
__device__ inline unsigned fbits(float f) {
  union { float f; unsigned u; } v; v.f = f; return v.u;
}
// Raw v_exp_f32 (2^x). NOT __exp2f (glibc macro collision, r10 compile fail).
__device__ inline float fexp2(float x) { return __builtin_amdgcn_exp2f(x); }

__device__ inline void load_lds16(const short* g, short* l) {
  __builtin_amdgcn_global_load_lds((const __attribute__((address_space(1))) void*)g,
                                   (__attribute__((address_space(3))) void*)l, 16, 0, 0);
}

// Merged fp32->bf16 conversion: ONE dispatch for x + all 4 weights.
// grid 12288: bid<8192 -> x (8192x1024 elems); else weight (bid-8192)>>10,
// local block (bid-8192)&1023. 256 thr x 4 elems = 1024 elems/block.
__global__ __launch_bounds__(256) void cvt_all(const float* __restrict__ x,
                                               const float* __restrict__ w0, const float* __restrict__ w1,
                                               const float* __restrict__ w2, const float* __restrict__ w3,
                                               short* __restrict__ ox,
                                               short* __restrict__ o0, short* __restrict__ o1,
                                               short* __restrict__ o2, short* __restrict__ o3) {
  const int bid = blockIdx.x;
  const float* in; short* out; int base;
  if (bid < 8192) {
    in = x; out = ox; base = bid << 10;
  } else {
    const int wb = bid - 8192;
    const int wsel = wb >> 10;
    base = (wb & 1023) << 10;
    switch (wsel) {
      case 0: in = w0; out = o0; break;
      case 1: in = w1; out = o1; break;
      case 2: in = w2; out = o2; break;
      default: in = w3; out = o3; break;
    }
  }
  const int i = base + threadIdx.x * 4;
  const float4 v = *(const float4*)(in + i);
  short4 o;
  o.x = f2bf(v.x); o.y = f2bf(v.y); o.z = f2bf(v.z); o.w = f2bf(v.w);
  *(short4*)(out + i) = o;
}

// fp32 -> bf16, 4 elems/thread (legacy, fallback paths).
__global__ __launch_bounds__(256) void cvt_f32_bf16(const float* __restrict__ in,
                                                    short* __restrict__ out, int n) {
  const int i = (blockIdx.x * 256 + threadIdx.x) * 4;
  if (i < n) {
    const float4 v = *(const float4*)(in + i);
    short4 o;
    o.x = f2bf(v.x); o.y = f2bf(v.y); o.z = f2bf(v.z); o.w = f2bf(v.w);
    *(short4*)(out + i) = o;
  }
}

// ---- BK=64 pipelined GEMM core (128^2, 2-phase, fallback paths) -------
__device__ inline void stage_tile64(const short* __restrict__ g, int ld, int k0,
                                    short* l, int tid) {
  const int srow = tid >> 3;
  const int scol = (tid & 7) * 8;
  const int scg  = ((tid & 7) ^ ((tid >> 3) & 7)) * 8;
  for (int j = 0; j < 4; j++)
    load_lds16(&g[(size_t)(srow + j * 32) * ld + k0 + scg], &l[(srow + j * 32) * 64 + scol]);
}

__device__ inline void mfma_core64(const short* lA, const short* lB, int wm, int wn,
                                   int col, int quad, f32x4 acc[4][4]) {
  for (int ks = 0; ks < 2; ks++) {
    const int cs = ((ks * 4 + quad) ^ (col & 7)) * 8;
    bf16x8 af[4], bfr[4];
    for (int i = 0; i < 4; i++) af[i]  = *(const bf16x8*)&lA[(wm + i * 16 + col) * 64 + cs];
    for (int j = 0; j < 4; j++) bfr[j] = *(const bf16x8*)&lB[(wn + j * 16 + col) * 64 + cs];
    for (int i = 0; i < 4; i++)
      for (int j = 0; j < 4; j++)
        acc[i][j] = __builtin_amdgcn_mfma_f32_16x16x32_bf16(af[i], bfr[j], acc[i][j], 0, 0, 0);
  }
}

// Generic bf16 GEMM (fallback): BK=64, dbuf, 2-phase. grid (M/128, N/128).
template <bool CF32>
__global__ __launch_bounds__(256) void gemm_bb(const short* __restrict__ A,
                                               const short* __restrict__ Bt,
                                               void* __restrict__ Cv,
                                               const float* __restrict__ bias,
                                               int M, int N, int K) {
  __shared__ __align__(16) short lA[2][128 * 64];
  __shared__ __align__(16) short lB[2][128 * 64];
  const int tid = threadIdx.x;
  const int wave = tid >> 6, lane = tid & 63;
  const int quad = lane >> 4, col = lane & 15;
  const int m0 = blockIdx.x * 128, n0 = blockIdx.y * 128;
  const int wm = (wave >> 1) * 64, wn = (wave & 1) * 64;

  f32x4 acc[4][4];
  for (int i = 0; i < 4; i++)
    for (int j = 0; j < 4; j++) acc[i][j] = (f32x4){0.f, 0.f, 0.f, 0.f};

  const int NT = K >> 6;
  stage_tile64(&A[(size_t)m0 * K], K, 0, lA[0], tid);
  stage_tile64(&Bt[(size_t)n0 * K], K, 0, lB[0], tid);
  __syncthreads();
  for (int kt = 0; kt < NT; kt++) {
    const int cur = kt & 1;
    if (kt + 1 < NT) {
      stage_tile64(&A[(size_t)m0 * K], K, (kt + 1) * 64, lA[cur ^ 1], tid);
      stage_tile64(&Bt[(size_t)n0 * K], K, (kt + 1) * 64, lB[cur ^ 1], tid);
    }
    mfma_core64(lA[cur], lB[cur], wm, wn, col, quad, acc);
    __syncthreads();
  }

  for (int j = 0; j < 4; j++) {
    const int gn = n0 + wn + j * 16 + col;
    const float bv = bias ? bias[gn] : 0.f;
    for (int i = 0; i < 4; i++) {
      const int gm = m0 + wm + i * 16 + quad * 4;
      for (int r = 0; r < 4; r++) {
        if (CF32) ((float*)Cv)[(size_t)(gm + r) * N + gn] = acc[i][j][r] + bv;
        else      ((short*)Cv)[(size_t)(gm + r) * N + gn] = f2bf(acc[i][j][r] + bv);
      }
    }
  }
}

// ---- v4 pipelined core: BM=128 x BN=256, triple-buffered, counted vmcnt,
// ONE barrier per K-tile. Kept for gemm_qkv8 (r15: dropped below top-5 cutoff
// 63.6us vs v3's 65.4 -> positive evidence). Dependence audit in r14 notes.
// grid (M/128, 12) -- BM=128.
__global__ __launch_bounds__(512, 2) void gemm_qkv8(const short* __restrict__ A,
                                                    const short* Wq, const short* Wk, const short* Wv,
                                                    short* Cq, short* Ck, short* Cvt) {
  __shared__ __align__(16) short lds[3][24576];  // [buf][A 128x64 | B 256x64]
  const int tid = threadIdx.x;
  const int wave = tid >> 6, lane = tid & 63;
  const int quad = lane >> 4, col = lane & 15;
  const int nsel = blockIdx.y >> 2;
  const int n0 = (blockIdx.y & 3) * 256;
  const short* Bt = nsel == 0 ? Wq : (nsel == 1 ? Wk : Wv);
  const int m0 = blockIdx.x * 128;
  const int wm = (wave >> 2) * 64, wn = (wave & 3) * 64;
  const int K = D_;
  const int NT = 16;  // K/64

  const int srow = tid >> 3;   // 0..63
  const int sc8 = tid & 7;
  const short* gA = &A[(size_t)m0 * K];
  const short* gB = &Bt[(size_t)n0 * K];

  auto stageA = [&](int t, int p) {  // p = 0..1 (64 rows each)
    const int row = p * 64 + srow;
    load_lds16(&gA[(size_t)row * K + t * 64 + ((sc8 ^ (row & 7)) * 8)],
               &lds[t % 3][row * 64 + sc8 * 8]);
  };
  auto stageB = [&](int t, int p) {  // p = 0..3 (64 rows each)
    const int row = p * 64 + srow;
    load_lds16(&gB[(size_t)row * K + t * 64 + ((sc8 ^ (row & 7)) * 8)],
               &lds[t % 3][8192 + row * 64 + sc8 * 8]);
  };

  f32x4 acc[4][4];
#pragma unroll
  for (int i = 0; i < 4; i++)
#pragma unroll
    for (int j = 0; j < 4; j++) acc[i][j] = (f32x4){0.f, 0.f, 0.f, 0.f};

  // Prologue: tile0 (6 loads, oldest) then tile1 (6).
  stageA(0, 0); stageA(0, 1);
  for (int p = 0; p < 4; p++) stageB(0, p);
  stageA(1, 0); stageA(1, 1);
  for (int p = 0; p < 4; p++) stageB(1, p);
  asm volatile("s_waitcnt vmcnt(6)" ::: "memory");  // tile0's 6 landed
  __builtin_amdgcn_sched_barrier(0);
  __builtin_amdgcn_s_barrier();

  for (int t = 0; t < NT; t++) {
    const short* la = lds[t % 3];
    const short* lb = la + 8192;

    bf16x8 af[4][2], bfr[4][2];
#pragma unroll
    for (int j = 0; j < 4; j++)
#pragma unroll
      for (int kk = 0; kk < 2; kk++)
        bfr[j][kk] = *(const bf16x8*)&lb[(wn + j * 16 + col) * 64 +
                                         (((kk * 4 + quad) ^ (col & 7)) * 8)];
#pragma unroll
    for (int f = 0; f < 4; f++)
#pragma unroll
      for (int kk = 0; kk < 2; kk++)
        af[f][kk] = *(const bf16x8*)&la[(wm + f * 16 + col) * 64 +
                                        (((kk * 4 + quad) ^ (col & 7)) * 8)];
    if (t + 2 < NT) {
      stageB(t + 2, 0); stageB(t + 2, 1); stageB(t + 2, 2); stageB(t + 2, 3);
      stageA(t + 2, 0); stageA(t + 2, 1);
    }
    __builtin_amdgcn_sched_barrier(0);
    asm volatile("s_waitcnt lgkmcnt(0)" ::: "memory");
    __builtin_amdgcn_sched_barrier(0);
    __builtin_amdgcn_s_setprio(1);
#pragma unroll
    for (int f = 0; f < 4; f++)
#pragma unroll
      for (int j = 0; j < 4; j++)
#pragma unroll
        for (int kk = 0; kk < 2; kk++)
          acc[f][j] = __builtin_amdgcn_mfma_f32_16x16x32_bf16(
              af[f][kk], bfr[j][kk], acc[f][j], 0, 0, 0);
    __builtin_amdgcn_s_setprio(0);
    if (t + 2 < NT)      { asm volatile("s_waitcnt vmcnt(6)" ::: "memory"); }
    else if (t + 1 < NT) { asm volatile("s_waitcnt vmcnt(0)" ::: "memory"); }
    __builtin_amdgcn_sched_barrier(0);
    __builtin_amdgcn_s_barrier();
  }

  if (nsel < 2) {
    short* C = nsel ? Ck : Cq;
    const float sc = nsel == 0 ? 0.18033688f : 1.0f;  // 0.125 * log2(e)
    for (int j = 0; j < 4; j++) {
      const int gn = n0 + wn + j * 16 + col;
      for (int i = 0; i < 4; i++) {
        const int gm = m0 + wm + i * 16 + quad * 4;
        for (int r = 0; r < 4; r++)
          C[(size_t)(gm + r) * D_ + gn] = f2bf(acc[i][j][r] * sc);
      }
    }
  } else {
    for (int j = 0; j < 4; j++) {
      const int gn = n0 + wn + j * 16 + col;
      for (int i = 0; i < 4; i++) {
        const int gm = m0 + wm + i * 16 + quad * 4;
        const int bb = gm >> 11, s = gm & 2047;
        short4 o;
        o.x = f2bf(acc[i][j][0]); o.y = f2bf(acc[i][j][1]);
        o.z = f2bf(acc[i][j][2]); o.w = f2bf(acc[i][j][3]);
        *(short4*)&Cvt[((size_t)bb * D_ + gn) * (size_t)S_ + s] = o;
      }
    }
  }
}

// Output projection, v3 TWO-PHASE schedule (reverted from v4: r15 total
// regressed +7.4us with both kernels on v4; qkv8 improved but bb8 is the
// suspect -- this round isolates it). r14-verified at total 230.6.
// grid (M/128, N/256) = (64, 4) = 256 blocks = exactly 1 resident round.
__global__ __launch_bounds__(512, 2) void gemm_bb8(const short* __restrict__ A,
                                                   const short* __restrict__ Bt,
                                                   float* __restrict__ C,
                                                   const float* __restrict__ bias) {
  __shared__ __align__(16) short lds[3][24576];  // [buf][A 128x64 | B 256x64]
  const int tid = threadIdx.x;
  const int wave = tid >> 6, lane = tid & 63;
  const int quad = lane >> 4, col = lane & 15;
  const int n0 = blockIdx.y * 256;
  const int m0 = blockIdx.x * 128;
  const int wm = (wave >> 2) * 64, wn = (wave & 3) * 64;
  const int K = D_, N = D_;
  const int NT = 16;  // K/64

  const int srow = tid >> 3;
  const int sc8 = tid & 7;
  const short* gA = &A[(size_t)m0 * K];
  const short* gB = &Bt[(size_t)n0 * K];

  auto stageA = [&](int t, int p) {
    const int row = p * 64 + srow;
    load_lds16(&gA[(size_t)row * K + t * 64 + ((sc8 ^ (row & 7)) * 8)],
               &lds[t % 3][row * 64 + sc8 * 8]);
  };
  auto stageB = [&](int t, int p) {
    const int row = p * 64 + srow;
    load_lds16(&gB[(size_t)row * K + t * 64 + ((sc8 ^ (row & 7)) * 8)],
               &lds[t % 3][8192 + row * 64 + sc8 * 8]);
  };

  f32x4 acc[4][4];
#pragma unroll
  for (int i = 0; i < 4; i++)
#pragma unroll
    for (int j = 0; j < 4; j++) acc[i][j] = (f32x4){0.f, 0.f, 0.f, 0.f};

  stageA(0, 0); stageA(0, 1);
  for (int p = 0; p < 4; p++) stageB(0, p);
  stageA(1, 0); stageA(1, 1);
  for (int p = 0; p < 4; p++) stageB(1, p);
  asm volatile("s_waitcnt vmcnt(6)" ::: "memory");
  __builtin_amdgcn_sched_barrier(0);
  __builtin_amdgcn_s_barrier();

  for (int t = 0; t < NT; t++) {
    const short* la = lds[t % 3];
    const short* lb = la + 8192;

    bf16x8 bfr[4][2];
    {
      bf16x8 af[2][2];
#pragma unroll
      for (int j = 0; j < 4; j++)
#pragma unroll
        for (int kk = 0; kk < 2; kk++)
          bfr[j][kk] = *(const bf16x8*)&lb[(wn + j * 16 + col) * 64 +
                                           (((kk * 4 + quad) ^ (col & 7)) * 8)];
#pragma unroll
      for (int f = 0; f < 2; f++)
#pragma unroll
        for (int kk = 0; kk < 2; kk++)
          af[f][kk] = *(const bf16x8*)&la[(wm + f * 16 + col) * 64 +
                                          (((kk * 4 + quad) ^ (col & 7)) * 8)];
      if (t + 2 < NT) { stageB(t + 2, 0); stageB(t + 2, 1); stageB(t + 2, 2); }
      __builtin_amdgcn_sched_barrier(0);
      __builtin_amdgcn_s_barrier();
      asm volatile("s_waitcnt lgkmcnt(0)" ::: "memory");
      __builtin_amdgcn_sched_barrier(0);
      __builtin_amdgcn_s_setprio(1);
#pragma unroll
      for (int f = 0; f < 2; f++)
#pragma unroll
        for (int j = 0; j < 4; j++)
#pragma unroll
          for (int kk = 0; kk < 2; kk++)
            acc[f][j] = __builtin_amdgcn_mfma_f32_16x16x32_bf16(
                af[f][kk], bfr[j][kk], acc[f][j], 0, 0, 0);
      __builtin_amdgcn_s_setprio(0);
      __builtin_amdgcn_sched_barrier(0);
      __builtin_amdgcn_s_barrier();
    }
    {
      bf16x8 af[2][2];
#pragma unroll
      for (int f = 0; f < 2; f++)
#pragma unroll
        for (int kk = 0; kk < 2; kk++)
          af[f][kk] = *(const bf16x8*)&la[(wm + (2 + f) * 16 + col) * 64 +
                                          (((kk * 4 + quad) ^ (col & 7)) * 8)];
      if (t + 2 < NT) { stageB(t + 2, 3); stageA(t + 2, 0); stageA(t + 2, 1); }
      __builtin_amdgcn_sched_barrier(0);
      __builtin_amdgcn_s_barrier();
      asm volatile("s_waitcnt lgkmcnt(0)" ::: "memory");
      __builtin_amdgcn_sched_barrier(0);
      __builtin_amdgcn_s_setprio(1);
#pragma unroll
      for (int f = 0; f < 2; f++)
#pragma unroll
        for (int j = 0; j < 4; j++)
#pragma unroll
          for (int kk = 0; kk < 2; kk++)
            acc[2 + f][j] = __builtin_amdgcn_mfma_f32_16x16x32_bf16(
                af[f][kk], bfr[j][kk], acc[2 + f][j], 0, 0, 0);
      __builtin_amdgcn_s_setprio(0);
      if (t + 2 < NT)      { asm volatile("s_waitcnt vmcnt(6)" ::: "memory"); }
      else if (t + 1 < NT) { asm volatile("s_waitcnt vmcnt(0)" ::: "memory"); }
      __builtin_amdgcn_sched_barrier(0);
      __builtin_amdgcn_s_barrier();
    }
  }

  for (int j = 0; j < 4; j++) {
    const int gn = n0 + wn + j * 16 + col;
    const float bv = bias[gn];
    for (int i = 0; i < 4; i++) {
      const int gm = m0 + wm + i * 16 + quad * 4;
      for (int r = 0; r < 4; r++)
        C[(size_t)(gm + r) * N + gn] = acc[i][j][r] + bv;
    }
  }
}

// Flash attention v10: raw v_exp_f32 via __builtin_amdgcn_exp2f (verified
// r15: 64.0us, VALUBusy 58->40 as predicted).
__global__ __launch_bounds__(256) void flash_attn6(const short* __restrict__ Q,
                                                   const short* __restrict__ Kt,
                                                   const short* __restrict__ Vt,
                                                   short* __restrict__ O) {
  __shared__ __align__(16) short lK[2][64 * 64];
  __shared__ __align__(16) short lV[2][64 * 64];
  __shared__ __align__(16) short pl[4][16 * 64];
  const int tid = threadIdx.x, wave = tid >> 6, lane = tid & 63;
  const int quad = lane >> 4, col = lane & 15;
  const int bh = blockIdx.x;
  const int b = bh >> 4, h = bh & 15;
  const size_t qkbase = (size_t)b * S_ * D_ + (size_t)h * HS_;
  const size_t vtbase = ((size_t)b * D_ + (size_t)h * HS_) * (size_t)S_;

  const int srow = tid >> 3;
  const int scg = (tid & 7) ^ (srow & 7);
  const int cs0 = (quad ^ (col & 7)) * 8;
  const int cs1 = ((quad + 4) ^ (col & 7)) * 8;
  short* plw = pl[wave];

  bf16x8 ones;
  for (int i = 0; i < 8; i++) ones[i] = (short)0x3F80;

  int nb = 0;

  for (int half = 0; half < 2; half++) {
    const int s = half ? (int)blockIdx.y : 31 - (int)blockIdx.y;
    const int qmin = s * 64 + wave * 16;
    const int L = s;

    load_lds16(&Kt[qkbase + (size_t)srow * D_ + scg * 8],        &lK[nb][tid * 8]);
    load_lds16(&Kt[qkbase + (size_t)(32 + srow) * D_ + scg * 8], &lK[nb][2048 + tid * 8]);
    load_lds16(&Vt[vtbase + (size_t)srow * S_ + scg * 8],        &lV[nb][tid * 8]);
    load_lds16(&Vt[vtbase + (size_t)(srow + 32) * S_ + scg * 8], &lV[nb][2048 + tid * 8]);
    const int cur0 = nb;
    nb ^= 1;

    bf16x8 qf[2];
    for (int x = 0; x < 2; x++)
      qf[x] = *(const bf16x8*)&Q[qkbase + (size_t)(qmin + col) * D_ + x * 32 + quad * 8];

    f32x4 oacc[4], lacc;
    for (int dt = 0; dt < 4; dt++) oacc[dt] = (f32x4){0.f, 0.f, 0.f, 0.f};
    lacc = (f32x4){0.f, 0.f, 0.f, 0.f};

    for (int nt = 0; nt <= L; nt++) {
      const int n0 = nt * 64;
      const int cur = cur0 ^ (nt & 1);
      __syncthreads();
      if (nt < L) {
        const int nn = n0 + 64;
        load_lds16(&Kt[qkbase + (size_t)(nn + srow) * D_ + scg * 8],      &lK[nb][tid * 8]);
        load_lds16(&Kt[qkbase + (size_t)(nn + 32 + srow) * D_ + scg * 8], &lK[nb][2048 + tid * 8]);
        load_lds16(&Vt[vtbase + (size_t)srow * S_ + nn + scg * 8],        &lV[nb][tid * 8]);
        load_lds16(&Vt[vtbase + (size_t)(srow + 32) * S_ + nn + scg * 8], &lV[nb][2048 + tid * 8]);
        nb ^= 1;
      }

      const short* lKc = lK[cur];
      const short* lVc = lV[cur];
      const bool needM = (nt == L);

      bf16x8 kf[4][2];
      for (int t = 0; t < 4; t++) {
        const int rb = (t * 16 + col) * 64;
        kf[t][0] = *(const bf16x8*)&lKc[rb + cs0];
        kf[t][1] = *(const bf16x8*)&lKc[rb + cs1];
      }

      const int qg = qmin + col;
      for (int t = 0; t < 4; t++) {
        f32x4 z = (f32x4){0.f, 0.f, 0.f, 0.f};
        __builtin_amdgcn_s_setprio(1);
        z = __builtin_amdgcn_mfma_f32_16x16x32_bf16(kf[t][0], qf[0], z, 0, 0, 0);
        z = __builtin_amdgcn_mfma_f32_16x16x32_bf16(kf[t][1], qf[1], z, 0, 0, 0);
        __builtin_amdgcn_s_setprio(0);
        float p0 = fexp2(z[0]);
        float p1 = fexp2(z[1]);
        float p2 = fexp2(z[2]);
        float p3 = fexp2(z[3]);
        if (needM) {
          const int kv = n0 + t * 16 + quad * 4;
          if (kv + 0 > qg) p0 = 0.f;
          if (kv + 1 > qg) p1 = 0.f;
          if (kv + 2 > qg) p2 = 0.f;
          if (kv + 3 > qg) p3 = 0.f;
        }
        unsigned d0 = __builtin_amdgcn_perm(fbits(p1), fbits(p0), 0x07060302u);
        unsigned d1 = __builtin_amdgcn_perm(fbits(p3), fbits(p2), 0x07060302u);
        const int cc = (2 * t + (quad >> 1)) ^ (col & 7);
        uint2 w; w.x = d0; w.y = d1;
        *(uint2*)&plw[col * 64 + cc * 8 + (quad & 1) * 4] = w;
      }

      for (int h2 = 0; h2 < 2; h2++) {
        const int cgo = ((h2 * 4 + quad) ^ (col & 7)) * 8;
        const bf16x8 pf = *(const bf16x8*)&plw[col * 64 + cgo];
        bf16x8 vf[4];
        for (int dt = 0; dt < 4; dt++)
          vf[dt] = *(const bf16x8*)&lVc[(dt * 16 + col) * 64 + cgo];
        __builtin_amdgcn_s_setprio(1);
        lacc = __builtin_amdgcn_mfma_f32_16x16x32_bf16(pf, ones, lacc, 0, 0, 0);
        for (int dt = 0; dt < 4; dt++)
          oacc[dt] = __builtin_amdgcn_mfma_f32_16x16x32_bf16(pf, vf[dt], oacc[dt], 0, 0, 0);
        __builtin_amdgcn_s_setprio(0);
      }
    }

    for (int r = 0; r < 4; r++) {
      const float inv = 1.f / lacc[r];
      const size_t row = qkbase + (size_t)(qmin + quad * 4 + r) * D_;
      for (int dt = 0; dt < 4; dt++)
        O[row + dt * 16 + col] = f2bf(oacc[dt][r] * inv);
    }
  }
}

// ---- legacy fallback kernels (small-ws paths) ----
__global__ __launch_bounds__(256) void gemm_ff(const float* __restrict__ A,
                                               const float* __restrict__ Bt,
                                               short* __restrict__ C,
                                               int M, int N, int K) {
  __shared__ __align__(16) short lA[128 * 32];
  __shared__ __align__(16) short lB[128 * 32];
  const int tid = threadIdx.x;
  const int wave = tid >> 6, lane = tid & 63;
  const int quad = lane >> 4, col = lane & 15;
  const int m0 = blockIdx.y * 128, n0 = blockIdx.x * 128;
  const int wm = (wave >> 1) * 64, wn = (wave & 1) * 64;
  const int srow2 = tid >> 1;
  const int sc = (tid & 1) * 16;

  f32x4 acc[4][4];
  for (int i = 0; i < 4; i++)
    for (int j = 0; j < 4; j++) acc[i][j] = (f32x4){0.f, 0.f, 0.f, 0.f};

  for (int k0 = 0; k0 < K; k0 += 32) {
    __syncthreads();
    {
      const float4* ga = (const float4*)&A[(size_t)(m0 + srow2) * K + k0 + sc];
      const float4 v0 = ga[0], v1 = ga[1], v2 = ga[2], v3 = ga[3];
      bf16x8 p0, p1;
      p0[0] = f2bf(v0.x); p0[1] = f2bf(v0.y); p0[2] = f2bf(v0.z); p0[3] = f2bf(v0.w);
      p0[4] = f2bf(v1.x); p0[5] = f2bf(v1.y); p0[6] = f2bf(v1.z); p0[7] = f2bf(v1.w);
      p1[0] = f2bf(v2.x); p1[1] = f2bf(v2.y); p1[2] = f2bf(v2.z); p1[3] = f2bf(v2.w);
      p1[4] = f2bf(v3.x); p1[5] = f2bf(v3.y); p1[6] = f2bf(v3.z); p1[7] = f2bf(v3.w);
      *(bf16x8*)&lA[srow2 * 32 + sc]     = p0;
      *(bf16x8*)&lA[srow2 * 32 + sc + 8] = p1;
    }
    {
      const float4* gb = (const float4*)&Bt[(size_t)(n0 + srow2) * K + k0 + sc];
      const float4 v0 = gb[0], v1 = gb[1], v2 = gb[2], v3 = gb[3];
      bf16x8 p0, p1;
      p0[0] = f2bf(v0.x); p0[1] = f2bf(v0.y); p0[2] = f2bf(v0.z); p0[3] = f2bf(v0.w);
      p0[4] = f2bf(v1.x); p0[5] = f2bf(v1.y); p0[6] = f2bf(v1.z); p0[7] = f2bf(v1.w);
      p1[0] = f2bf(v2.x); p1[1] = f2bf(v2.y); p1[2] = f2bf(v2.z); p1[3] = f2bf(v2.w);
      p1[4] = f2bf(v3.x); p1[5] = f2bf(v3.y); p1[6] = f2bf(v3.z); p1[7] = f2bf(v3.w);
      *(bf16x8*)&lB[srow2 * 32 + sc]     = p0;
      *(bf16x8*)&lB[srow2 * 32 + sc + 8] = p1;
    }
    __syncthreads();
    {
      bf16x8 af[4], bfr[4];
      for (int i = 0; i < 4; i++) af[i]  = *(const bf16x8*)&lA[(wm + i * 16 + col) * 32 + quad * 8];
      for (int j = 0; j < 4; j++) bfr[j] = *(const bf16x8*)&lB[(wn + j * 16 + col) * 32 + quad * 8];
      for (int i = 0; i < 4; i++)
        for (int j = 0; j < 4; j++)
          acc[i][j] = __builtin_amdgcn_mfma_f32_16x16x32_bf16(af[i], bfr[j], acc[i][j], 0, 0, 0);
    }
  }

  for (int j = 0; j < 4; j++) {
    const int gn = n0 + wn + j * 16 + col;
    for (int i = 0; i < 4; i++) {
      const int gm = m0 + wm + i * 16 + quad * 4;
      for (int r = 0; r < 4; r++)
        C[(size_t)(gm + r) * N + gn] = f2bf(acc[i][j][r]);
    }
  }
}

__global__ __launch_bounds__(256) void gemm_out_bf(const short* __restrict__ A,
                                                   const float* __restrict__ Bt,
                                                   float* __restrict__ C,
                                                   const float* __restrict__ bias,
                                                   int M, int N, int K) {
  __shared__ __align__(16) short lA[128 * 32];
  __shared__ __align__(16) short lB[128 * 32];
  const int tid = threadIdx.x;
  const int wave = tid >> 6, lane = tid & 63;
  const int quad = lane >> 4, col = lane & 15;
  const int m0 = blockIdx.y * 128, n0 = blockIdx.x * 128;
  const int wm = (wave >> 1) * 64, wn = (wave & 1) * 64;
  const int srow = wave * 32 + (lane >> 2);
  const int scol = (lane & 3) * 8;
  const int srow2 = tid >> 1;
  const int sc = (tid & 1) * 16;

  f32x4 acc[4][4];
  for (int i = 0; i < 4; i++)
    for (int j = 0; j < 4; j++) acc[i][j] = (f32x4){0.f, 0.f, 0.f, 0.f};

  for (int k0 = 0; k0 < K; k0 += 32) {
    __syncthreads();
    load_lds16(&A[(size_t)(m0 + srow) * K + k0 + scol],      &lA[srow * 32 + scol]);
    load_lds16(&A[(size_t)(m0 + srow + 16) * K + k0 + scol], &lA[(srow + 16) * 32 + scol]);
    {
      const float4* gb = (const float4*)&Bt[(size_t)(n0 + srow2) * K + k0 + sc];
      const float4 v0 = gb[0], v1 = gb[1], v2 = gb[2], v3 = gb[3];
      bf16x8 p0, p1;
      p0[0] = f2bf(v0.x); p0[1] = f2bf(v0.y); p0[2] = f2bf(v0.z); p0[3] = f2bf(v0.w);
      p0[4] = f2bf(v1.x); p0[5] = f2bf(v1.y); p0[6] = f2bf(v1.z); p0[7] = f2bf(v1.w);
      p1[0] = f2bf(v2.x); p1[1] = f2bf(v2.y); p1[2] = f2bf(v2.z); p1[3] = f2bf(v2.w);
      p1[4] = f2bf(v3.x); p1[5] = f2bf(v3.y); p1[6] = f2bf(v3.z); p1[7] = f2bf(v3.w);
      *(bf16x8*)&lB[srow2 * 32 + sc]     = p0;
      *(bf16x8*)&lB[srow2 * 32 + sc + 8] = p1;
    }
    __syncthreads();
    {
      bf16x8 af[4], bfr[4];
      for (int i = 0; i < 4; i++) af[i]  = *(const bf16x8*)&lA[(wm + i * 16 + col) * 32 + quad * 8];
      for (int j = 0; j < 4; j++) bfr[j] = *(const bf16x8*)&lB[(wn + j * 16 + col) * 32 + quad * 8];
      for (int i = 0; i < 4; i++)
        for (int j = 0; j < 4; j++)
          acc[i][j] = __builtin_amdgcn_mfma_f32_16x16x32_bf16(af[i], bfr[j], acc[i][j], 0, 0, 0);
    }
  }

  for (int j = 0; j < 4; j++) {
    const int gn = n0 + wn + j * 16 + col;
    const float bv = bias ? bias[gn] : 0.f;
    for (int i = 0; i < 4; i++) {
      const int gm = m0 + wm + i * 16 + quad * 4;
      for (int r = 0; r < 4; r++)
        C[(size_t)(gm + r) * N + gn] = acc[i][j][r] + bv;
    }
  }
}

__global__ __launch_bounds__(64) void flash_attn(const short* __restrict__ Q,
                                                 const short* __restrict__ K,
                                                 const short* __restrict__ V,
                                                 short* __restrict__ O) {
  __shared__ __align__(16) short pl[16 * 40];
  const int lane = threadIdx.x;
  const int quad = lane >> 4, col = lane & 15;
  const int blk = blockIdx.x;
  const int qt = blk & 127;
  const int bh = blk >> 7;
  const int b = bh >> 4, h = bh & 15;
  const int q0 = qt * 16;
  const size_t base = (size_t)b * S_ * D_ + (size_t)h * HS_;

  const bf16x8 qf0 = *(const bf16x8*)&Q[base + (size_t)(q0 + col) * D_ + quad * 8];
  const bf16x8 qf1 = *(const bf16x8*)&Q[base + (size_t)(q0 + col) * D_ + 32 + quad * 8];

  float mr[4], lr[4];
  f32x4 oacc[4];
  for (int r = 0; r < 4; r++) { mr[r] = -1e30f; lr[r] = 0.f; }
  for (int dt = 0; dt < 4; dt++) oacc[dt] = (f32x4){0.f, 0.f, 0.f, 0.f};

  const int ntiles = (q0 + 15) / 32 + 1;
  for (int nt = 0; nt < ntiles; nt++) {
    const int n0 = nt * 32;
    f32x4 s[2];
    s[0] = (f32x4){0.f, 0.f, 0.f, 0.f};
    s[1] = (f32x4){0.f, 0.f, 0.f, 0.f};
    for (int t = 0; t < 2; t++) {
      const short* kp = &K[base + (size_t)(n0 + t * 16 + col) * D_ + quad * 8];
      const bf16x8 kf0 = *(const bf16x8*)kp;
      const bf16x8 kf1 = *(const bf16x8*)(kp + 32);
      s[t] = __builtin_amdgcn_mfma_f32_16x16x32_bf16(qf0, kf0, s[t], 0, 0, 0);
      s[t] = __builtin_amdgcn_mfma_f32_16x16x32_bf16(qf1, kf1, s[t], 0, 0, 0);
    }
    for (int r = 0; r < 4; r++) {
      const int mg = q0 + quad * 4 + r;
      float s0 = s[0][r] * 0.125f; if (n0 + col > mg)      s0 = -1e30f;
      float s1 = s[1][r] * 0.125f; if (n0 + 16 + col > mg) s1 = -1e30f;
      float tm = fmaxf(s0, s1);
      for (int off = 1; off < 16; off <<= 1) tm = fmaxf(tm, __shfl_xor(tm, off));
      const float mnew = fmaxf(mr[r], tm);
      const float alpha = __expf(mr[r] - mnew);
      mr[r] = mnew;
      const float p0 = __expf(s0 - mnew);
      const float p1 = __expf(s1 - mnew);
      float ps = p0 + p1;
      for (int off = 1; off < 16; off <<= 1) ps += __shfl_xor(ps, off);
      lr[r] = lr[r] * alpha + ps;
      for (int dt = 0; dt < 4; dt++) oacc[dt][r] *= alpha;
      pl[(quad * 4 + r) * 40 + col]      = f2bf(p0);
      pl[(quad * 4 + r) * 40 + 16 + col] = f2bf(p1);
    }
    const bf16x8 pf = *(const bf16x8*)&pl[col * 40 + quad * 8];
    for (int dt = 0; dt < 4; dt++) {
      bf16x8 vf;
      const short* vp = &V[base + (size_t)(n0 + quad * 8) * D_ + dt * 16 + col];
      for (int j = 0; j < 8; j++) vf[j] = vp[(size_t)j * D_];
      oacc[dt] = __builtin_amdgcn_mfma_f32_16x16x32_bf16(pf, vf, oacc[dt], 0, 0, 0);
    }
  }

  for (int r = 0; r < 4; r++) {
    const float inv = 1.f / lr[r];
    const size_t row = base + (size_t)(q0 + quad * 4 + r) * D_;
    for (int dt = 0; dt < 4; dt++)
      O[row + dt * 16 + col] = f2bf(oacc[dt][r] * inv);
  }
}

extern "C" void kernel_launch(void* const* d_in, const int* in_sizes, int n_in,
                              void* d_out, int out_size, void* d_ws, size_t ws_size,
                              hipStream_t stream) {
  const float* x  = (const float*)d_in[0];
  const float* Wk = (const float*)d_in[1];
  const float* Wq = (const float*)d_in[2];
  const float* Wv = (const float*)d_in[3];
  const float* Wo = (const float*)d_in[4];
  const float* bo = (const float*)d_in[5];
  float* out = (float*)d_out;

  char* ws = (char*)d_ws;
  const size_t MiB = 1u << 20;
  const int M = B_ * S_, N = D_, K = D_;
  const int nx = M * D_, nw = D_ * D_;

  if (ws_size >= 88 * MiB) {
    short* xb    = (short*)(ws);
    short* wkb   = (short*)(ws + 16 * MiB);
    short* wqb   = (short*)(ws + 18 * MiB);
    short* wvb   = (short*)(ws + 20 * MiB);
    short* wob   = (short*)(ws + 22 * MiB);
    short* q_ws  = (short*)(ws + 24 * MiB);
    short* k_ws  = (short*)(ws + 40 * MiB);
    short* vt_ws = (short*)(ws + 56 * MiB);
    short* a_ws  = (short*)(ws + 72 * MiB);

    hipLaunchKernelGGL(cvt_all, dim3(12288), dim3(256), 0, stream,
                       x, Wq, Wk, Wv, Wo, xb, wqb, wkb, wvb, wob);
    hipLaunchKernelGGL(gemm_qkv8, dim3(M / 128, 12), dim3(512), 0, stream,
                       xb, wqb, wkb, wvb, q_ws, k_ws, vt_ws);
    hipLaunchKernelGGL(flash_attn6, dim3(B_ * H_, 16), dim3(256), 0, stream,
                       q_ws, k_ws, vt_ws, a_ws);
    hipLaunchKernelGGL(gemm_bb8, dim3(M / 128, N / 256), dim3(512), 0, stream,
                       a_ws, wob, out, bo);
  } else if (ws_size >= 64 * MiB) {
    short* q_ws = (short*)(ws);
    short* k_ws = (short*)(ws + 16 * MiB);
    short* v_ws = (short*)(ws + 32 * MiB);
    short* a_ws = (short*)(ws + 48 * MiB);
    dim3 gg(N / 128, M / 128), gb(256);
    hipLaunchKernelGGL(gemm_ff, gg, gb, 0, stream, x, Wq, q_ws, M, N, K);
    hipLaunchKernelGGL(gemm_ff, gg, gb, 0, stream, x, Wk, k_ws, M, N, K);
    hipLaunchKernelGGL(gemm_ff, gg, gb, 0, stream, x, Wv, v_ws, M, N, K);
    hipLaunchKernelGGL(flash_attn, dim3(B_ * H_ * (S_ / 16)), dim3(64), 0, stream, q_ws, k_ws, v_ws, a_ws);
    hipLaunchKernelGGL(gemm_out_bf, gg, gb, 0, stream, a_ws, Wo, out, bo, M, N, K);
  } else {
    short* q_ws = (short*)(ws);
    short* k_ws = (short*)(ws + 4 * MiB);
    short* v_ws = (short*)(ws + 8 * MiB);
    short* a_ws = (short*)(ws + 12 * MiB);
    const int Mb = S_;
    dim3 gg(N / 128, Mb / 128), gb(256);
    for (int b = 0; b < B_; b++) {
      const float* xb = x + (size_t)b * S_ * D_;
      float* ob = out + (size_t)b * S_ * D_;
      hipLaunchKernelGGL(gemm_ff, gg, gb, 0, stream, xb, Wq, q_ws, Mb, N, K);
      hipLaunchKernelGGL(gemm_ff, gg, gb, 0, stream, xb, Wk, k_ws, Mb, N, K);
      hipLaunchKernelGGL(gemm_ff, gg, gb, 0, stream, xb, Wv, v_ws, Mb, N, K);
      hipLaunchKernelGGL(flash_attn, dim3(H_ * (S_ / 16)), dim3(64), 0, stream, q_ws, k_ws, v_ws, a_ws);
      hipLaunchKernelGGL(gemm_out_bf, gg, gb, 0, stream, a_ws, Wo, ob, bo, Mb, N, K);
    }
  }
}